// Round 1
// baseline (724.950 us; speedup 1.0000x reference)
//
#include <hip/hip_runtime.h>
#include <math.h>

typedef __bf16 bf16;
typedef bf16 bf16x8 __attribute__((ext_vector_type(8)));
typedef bf16 bf16x4 __attribute__((ext_vector_type(4)));
typedef float f32x4 __attribute__((ext_vector_type(4)));

// Problem constants
#define BB 2
#define SS 2048
#define HIDN 2048
#define NH 16
#define NKV 4
#define DD 128
#define NROT 64

__device__ __forceinline__ float waveAllReduceSum(float v) {
#pragma unroll
  for (int o = 1; o < 64; o <<= 1) v += __shfl_xor(v, o, 64);
  return v;
}

// ---------------- convert f32 -> bf16 ----------------
__global__ __launch_bounds__(256) void cvt_bf16_k(const float* __restrict__ in,
                                                  bf16* __restrict__ out, int n) {
  int i = (blockIdx.x * 256 + threadIdx.x) * 4;
  if (i + 3 < n) {
    float4 v = *reinterpret_cast<const float4*>(in + i);
    bf16x4 o = {(bf16)v.x, (bf16)v.y, (bf16)v.z, (bf16)v.w};
    *reinterpret_cast<bf16x4*>(out + i) = o;
  }
}

// ---------------- transpose + convert: W (K x N) f32 -> WT (N x K) bf16 ----------------
__global__ __launch_bounds__(256) void transpose_cvt(const float* __restrict__ W,
                                                     bf16* __restrict__ WT, int K, int N) {
  __shared__ bf16 tile[64][72];
  int n0 = blockIdx.x * 64, k0 = blockIdx.y * 64;
  int tx = threadIdx.x & 63, ty = threadIdx.x >> 6;
#pragma unroll
  for (int i = 0; i < 16; i++) {
    int k = ty + i * 4;
    tile[k][tx] = (bf16)W[(size_t)(k0 + k) * N + n0 + tx];
  }
  __syncthreads();
#pragma unroll
  for (int i = 0; i < 16; i++) {
    int n = ty + i * 4;
    WT[(size_t)(n0 + n) * K + k0 + tx] = tile[tx][n];
  }
}

// ---------------- GEMM: C(MxN) = A(MxK) @ Bt(NxK)^T, bf16 in, CT out ----------------
// 128x128 tile, BK=64, 4 waves (2x2 of 64x64), mfma 16x16x32 bf16.
// LDS XOR-swizzle: 16B-slot index ^= (row&7)  (2-way conflicts only).
template <typename CT>
__global__ __launch_bounds__(256) void gemm_bt(const bf16* __restrict__ A,
                                               const bf16* __restrict__ Bt,
                                               CT* __restrict__ C, int M, int N, int K) {
  __shared__ bf16 lA[128 * 64];
  __shared__ bf16 lB[128 * 64];
  const int nbx = N >> 7;
  int bx = blockIdx.x % nbx, by = blockIdx.x / nbx;
  const int t = threadIdx.x;
  const int l = t & 63, w = t >> 6;
  const int wr = w >> 1, wc = w & 1;
  const int lr = l & 15, lhi = l >> 4;

  f32x4 acc[4][4];
#pragma unroll
  for (int m = 0; m < 4; m++)
#pragma unroll
    for (int n = 0; n < 4; n++) acc[m][n] = f32x4{0.f, 0.f, 0.f, 0.f};

  const int rowA0 = by * 128, rowB0 = bx * 128;
  const int nkt = K >> 6;
  for (int kt = 0; kt < nkt; ++kt) {
    __syncthreads();
#pragma unroll
    for (int it = 0; it < 4; ++it) {
      int slot = it * 256 + t;
      int row = slot >> 3, sl = slot & 7;
      bf16x8 va = *reinterpret_cast<const bf16x8*>(A + (size_t)(rowA0 + row) * K + kt * 64 + sl * 8);
      *reinterpret_cast<bf16x8*>((char*)lA + row * 128 + ((sl ^ (row & 7)) << 4)) = va;
      bf16x8 vb = *reinterpret_cast<const bf16x8*>(Bt + (size_t)(rowB0 + row) * K + kt * 64 + sl * 8);
      *reinterpret_cast<bf16x8*>((char*)lB + row * 128 + ((sl ^ (row & 7)) << 4)) = vb;
    }
    __syncthreads();
#pragma unroll
    for (int kc = 0; kc < 2; ++kc) {
      bf16x8 af[4], bg[4];
#pragma unroll
      for (int m = 0; m < 4; m++) {
        int row = wr * 64 + m * 16 + lr;
        af[m] = *reinterpret_cast<const bf16x8*>((char*)lA + row * 128 + (((kc * 4 + lhi) ^ (row & 7)) << 4));
      }
#pragma unroll
      for (int n = 0; n < 4; n++) {
        int row = wc * 64 + n * 16 + lr;
        bg[n] = *reinterpret_cast<const bf16x8*>((char*)lB + row * 128 + (((kc * 4 + lhi) ^ (row & 7)) << 4));
      }
#pragma unroll
      for (int m = 0; m < 4; m++)
#pragma unroll
        for (int n = 0; n < 4; n++)
          acc[m][n] = __builtin_amdgcn_mfma_f32_16x16x32_bf16(af[m], bg[n], acc[m][n], 0, 0, 0);
    }
  }
#pragma unroll
  for (int m = 0; m < 4; m++)
#pragma unroll
    for (int n = 0; n < 4; n++)
#pragma unroll
      for (int r = 0; r < 4; r++) {
        int grow = rowA0 + wr * 64 + m * 16 + lhi * 4 + r;
        int gcol = rowB0 + wc * 64 + n * 16 + lr;
        C[(size_t)grow * N + gcol] = (CT)acc[m][n][r];
      }
}

// ---------------- Threefry-2x32 (JAX), key (0,42) -> gumbel ----------------
__device__ __forceinline__ unsigned rotl32(unsigned x, int r) { return (x << r) | (x >> (32 - r)); }

__device__ __forceinline__ float gumbel42(unsigned i) {
  const unsigned half = (unsigned)(BB * SS * DD) / 2u;  // 262144
  unsigned x0, x1;
  int word;
  if (i < half) { x0 = i; x1 = i + half; word = 0; }
  else          { x0 = i - half; x1 = i; word = 1; }
  const unsigned k0 = 0u, k1 = 42u;
  const unsigned k2 = k0 ^ k1 ^ 0x1BD11BDAu;
  x0 += k0; x1 += k1;
#define TF_R(r) { x0 += x1; x1 = rotl32(x1, r); x1 ^= x0; }
  TF_R(13) TF_R(15) TF_R(26) TF_R(6)
  x0 += k1; x1 += k2 + 1u;
  TF_R(17) TF_R(29) TF_R(16) TF_R(24)
  x0 += k2; x1 += k0 + 2u;
  TF_R(13) TF_R(15) TF_R(26) TF_R(6)
  x0 += k0; x1 += k1 + 3u;
  TF_R(17) TF_R(29) TF_R(16) TF_R(24)
  x0 += k1; x1 += k2 + 4u;
  TF_R(13) TF_R(15) TF_R(26) TF_R(6)
  x0 += k2; x1 += k0 + 5u;
#undef TF_R
  unsigned bits = word ? x1 : x0;
  float u = __uint_as_float((bits >> 9) | 0x3f800000u) - 1.0f;  // [0,1)
  float ex = -log1pf(-u);   // exponential sample
  return -logf(ex);         // gumbel
}

// ---------------- mask kernel: LN -> gelu -> @Wd -> +gumbel -> sigmoid -> round ----------------
__global__ __launch_bounds__(128) void mask_kernel(const bf16* __restrict__ embb,
                                                   const float* __restrict__ rnn,
                                                   const float* __restrict__ lng,
                                                   const float* __restrict__ lnb,
                                                   const float* __restrict__ Wd,
                                                   bf16* __restrict__ maskb) {
  int row = blockIdx.x;  // b*S+s
  int t = threadIdx.x;   // 0..127
  int l = t & 63, w = t >> 6;
  __shared__ float redm[2], redv[2], gsh[128];
  float e = (float)embb[(size_t)row * 128 + t] + rnn[t];
  float s1 = waveAllReduceSum(e);
  if (l == 0) redm[w] = s1;
  __syncthreads();
  float mu = (redm[0] + redm[1]) * (1.0f / 128.0f);
  float dv = (e - mu) * (e - mu);
  float s2 = waveAllReduceSum(dv);
  if (l == 0) redv[w] = s2;
  __syncthreads();
  float var = (redv[0] + redv[1]) * (1.0f / 128.0f);
  float ln = (e - mu) * rsqrtf(var + 1e-5f) * lng[t] + lnb[t];
  float g = 0.5f * ln * (1.0f + erff(ln * 0.7071067811865475f));
  gsh[t] = g;
  __syncthreads();
  float logit = 0.f;
#pragma unroll 8
  for (int e2 = 0; e2 < 128; e2++) logit += gsh[e2] * Wd[e2 * 128 + t];
  float gum = gumbel42((unsigned)(row * 128 + t));
  float x = (logit + gum + 3.0f) * 2.5f;  // /TAU
  float y = 1.0f / (1.0f + expf(-x));
  maskb[(size_t)row * 128 + t] = (bf16)rintf(y);
}

// ---------------- q/gate: RMSNorm, mask, RoPE, scale; store Q[b,h,s,d], sgate[b,h,s,d] ----------------
__global__ __launch_bounds__(128) void qgate_kernel(const bf16* __restrict__ qkv,
                                                    const bf16* __restrict__ maskb,
                                                    const float* __restrict__ qw,
                                                    const float* __restrict__ cosT,
                                                    const float* __restrict__ sinT,
                                                    bf16* __restrict__ wq,
                                                    bf16* __restrict__ sgate) {
  int idx = blockIdx.x;
  int h = idx & 15;
  int row = idx >> 4;  // b*S+s
  int b = row >> 11, s = row & 2047;
  int d = threadIdx.x;
  int l = d & 63, w = d >> 6;
  __shared__ float sq[128];
  __shared__ float red2[2];
  float qv = (float)qkv[(size_t)row * 4096 + h * 256 + d];
  float gv = (float)qkv[(size_t)row * 4096 + h * 256 + 128 + d];
  float ss = waveAllReduceSum(qv * qv);
  if (l == 0) red2[w] = ss;
  __syncthreads();
  float ms = (red2[0] + red2[1]) * (1.0f / 128.0f);
  float qn = qv * rsqrtf(ms + 1e-6f) * (1.0f + qw[d]);
  float qm = qn * (float)maskb[(size_t)row * 128 + d];
  sq[d] = qm;
  __syncthreads();
  float outv;
  if (d < 64) {
    float c = cosT[(size_t)row * 64 + d];
    float si = sinT[(size_t)row * 64 + d];
    float other = (d < 32) ? -sq[d + 32] : sq[d - 32];
    outv = qm * c + other * si;
  } else outv = qm;
  outv *= 0.08838834764831845f;  // 1/sqrt(128), folded into Q
  size_t o = ((size_t)((b * 16 + h) * 2048 + s)) * 128 + d;
  wq[o] = (bf16)outv;
  sgate[o] = (bf16)(1.0f / (1.0f + expf(-gv)));
}

// ---------------- k: RMSNorm, mask, RoPE; store K[b,kv,s,d] ----------------
__global__ __launch_bounds__(128) void k_kernel(const bf16* __restrict__ kraw,
                                                const bf16* __restrict__ maskb,
                                                const float* __restrict__ kw,
                                                const float* __restrict__ cosT,
                                                const float* __restrict__ sinT,
                                                bf16* __restrict__ wk) {
  int idx = blockIdx.x;
  int kv = idx & 3;
  int row = idx >> 2;  // b*S+s
  int b = row >> 11, s = row & 2047;
  int d = threadIdx.x;
  int l = d & 63, w = d >> 6;
  __shared__ float sk[128];
  __shared__ float red2[2];
  float kval = (float)kraw[(size_t)row * 512 + kv * 128 + d];
  float ss = waveAllReduceSum(kval * kval);
  if (l == 0) red2[w] = ss;
  __syncthreads();
  float ms = (red2[0] + red2[1]) * (1.0f / 128.0f);
  float kn = kval * rsqrtf(ms + 1e-6f) * (1.0f + kw[d]);
  float km = kn * (float)maskb[(size_t)row * 128 + d];
  sk[d] = km;
  __syncthreads();
  float outv;
  if (d < 64) {
    float c = cosT[(size_t)row * 64 + d];
    float si = sinT[(size_t)row * 64 + d];
    float other = (d < 32) ? -sk[d + 32] : sk[d - 32];
    outv = km * c + other * si;
  } else outv = km;
  wk[((size_t)((b * 4 + kv) * 2048 + s)) * 128 + d] = (bf16)outv;
}

// ---------------- v transpose: vraw[b,s,kv*128+d] -> wvt[b,kv,d,s] ----------------
__global__ __launch_bounds__(256) void vt_kernel(const bf16* __restrict__ vraw,
                                                 bf16* __restrict__ wvt) {
  int dt = blockIdx.x & 1;
  int st = (blockIdx.x >> 1) & 31;
  int bkv = blockIdx.x >> 6;
  int b = bkv >> 2, kv = bkv & 3;
  __shared__ bf16 tl[64][72];
  int tx = threadIdx.x & 63, ty = threadIdx.x >> 6;
  int s0 = st * 64, d0 = dt * 64;
#pragma unroll
  for (int i = 0; i < 16; i++) {
    int srow = ty + i * 4;
    tl[srow][tx] = vraw[(size_t)(b * 2048 + s0 + srow) * 512 + kv * 128 + d0 + tx];
  }
  __syncthreads();
#pragma unroll
  for (int i = 0; i < 16; i++) {
    int drow = ty + i * 4;
    wvt[(size_t)((b * 4 + kv) * 128 + d0 + drow) * 2048 + s0 + tx] = tl[tx][drow];
  }
}

// ---------------- flash attention, causal, GQA 4:1, fused *sigmoid(gate) ----------------
__global__ __launch_bounds__(256) void attn_kernel(const bf16* __restrict__ wq,
                                                   const bf16* __restrict__ wk,
                                                   const bf16* __restrict__ wvt,
                                                   const bf16* __restrict__ sgate,
                                                   bf16* __restrict__ wattn) {
  __shared__ bf16 lK[64 * 128];   // [kv 64][d 128], swizzled
  __shared__ bf16 lV[128 * 64];   // [d 128][kv 64], swizzled
  __shared__ bf16 lP[4][16 * 64]; // per-wave P, swizzled
  int qb = blockIdx.x & 31;
  int bh = blockIdx.x >> 5;
  int b = bh >> 4, h = bh & 15, kvh = h >> 2;
  int t = threadIdx.x, l = t & 63, w = t >> 6;
  int lr = l & 15, lhi = l >> 4;

  const bf16* qbase = wq + (size_t)((b * 16 + h) * 2048 + qb * 64 + w * 16) * 128;
  bf16x8 aq[4];
#pragma unroll
  for (int kc = 0; kc < 4; kc++)
    aq[kc] = *reinterpret_cast<const bf16x8*>(qbase + (size_t)lr * 128 + kc * 32 + lhi * 8);

  f32x4 oacc[8];
#pragma unroll
  for (int db = 0; db < 8; db++) oacc[db] = f32x4{0.f, 0.f, 0.f, 0.f};
  float m_run[4], l_run[4];
#pragma unroll
  for (int r = 0; r < 4; r++) { m_run[r] = -1e38f; l_run[r] = 0.f; }

  const bf16* kbase = wk + (size_t)((b * 4 + kvh) * 2048) * 128;
  const bf16* vbase = wvt + (size_t)((b * 4 + kvh) * 128) * 2048;

  int nt = qb + 1;
  for (int tt = 0; tt < nt; ++tt) {
    __syncthreads();
#pragma unroll
    for (int it = 0; it < 4; ++it) {
      int slot = it * 256 + t;
      int row = slot >> 4, sl = slot & 15;
      bf16x8 v = *reinterpret_cast<const bf16x8*>(kbase + (size_t)(tt * 64 + row) * 128 + sl * 8);
      *reinterpret_cast<bf16x8*>((char*)lK + row * 256 + ((sl ^ (row & 7)) << 4)) = v;
      int row2 = slot >> 3, sl2 = slot & 7;
      bf16x8 v2 = *reinterpret_cast<const bf16x8*>(vbase + (size_t)row2 * 2048 + tt * 64 + sl2 * 8);
      *reinterpret_cast<bf16x8*>((char*)lV + row2 * 128 + ((sl2 ^ (row2 & 7)) << 4)) = v2;
    }
    __syncthreads();

    f32x4 sacc[4];
#pragma unroll
    for (int j = 0; j < 4; j++) sacc[j] = f32x4{0.f, 0.f, 0.f, 0.f};
#pragma unroll
    for (int kc = 0; kc < 4; kc++)
#pragma unroll
      for (int j = 0; j < 4; j++) {
        int row = j * 16 + lr;
        bf16x8 bk = *reinterpret_cast<const bf16x8*>((char*)lK + row * 256 + (((kc * 4 + lhi) ^ (row & 7)) << 4));
        sacc[j] = __builtin_amdgcn_mfma_f32_16x16x32_bf16(aq[kc], bk, sacc[j], 0, 0, 0);
      }

    if (tt == nt - 1) {  // diagonal tile: causal mask
#pragma unroll
      for (int j = 0; j < 4; j++) {
        int col = tt * 64 + j * 16 + lr;
#pragma unroll
        for (int r = 0; r < 4; r++) {
          int rowg = qb * 64 + w * 16 + lhi * 4 + r;
          if (col > rowg) sacc[j][r] = -1e30f;
        }
      }
    }

    float pr[4][4];
#pragma unroll
    for (int r = 0; r < 4; r++) {
      float mx = fmaxf(fmaxf(sacc[0][r], sacc[1][r]), fmaxf(sacc[2][r], sacc[3][r]));
#pragma unroll
      for (int o = 1; o < 16; o <<= 1) mx = fmaxf(mx, __shfl_xor(mx, o, 64));
      float mnew = fmaxf(m_run[r], mx);
      float corr = __expf(m_run[r] - mnew);
      float rs = 0.f;
#pragma unroll
      for (int j = 0; j < 4; j++) {
        float p = __expf(sacc[j][r] - mnew);
        pr[j][r] = p;
        rs += p;
      }
#pragma unroll
      for (int o = 1; o < 16; o <<= 1) rs += __shfl_xor(rs, o, 64);
      l_run[r] = l_run[r] * corr + rs;
      m_run[r] = mnew;
#pragma unroll
      for (int db = 0; db < 8; db++) oacc[db][r] *= corr;
    }

    char* pb = (char*)(&lP[w][0]);
#pragma unroll
    for (int j = 0; j < 4; j++)
#pragma unroll
      for (int r = 0; r < 4; r++) {
        int prow = lhi * 4 + r;
        int pcolb = (j * 16 + lr) * 2;
        *reinterpret_cast<bf16*>(pb + prow * 128 + (pcolb ^ ((prow & 7) << 4))) = (bf16)pr[j][r];
      }
    bf16x8 pa[2];
#pragma unroll
    for (int kc2 = 0; kc2 < 2; kc2++)
      pa[kc2] = *reinterpret_cast<const bf16x8*>(pb + lr * 128 + ((kc2 * 64 + lhi * 16) ^ ((lr & 7) << 4)));
#pragma unroll
    for (int kc2 = 0; kc2 < 2; kc2++)
#pragma unroll
      for (int db = 0; db < 8; db++) {
        int row = db * 16 + lr;
        bf16x8 bv = *reinterpret_cast<const bf16x8*>((char*)lV + row * 128 + (((kc2 * 4 + lhi) ^ (row & 7)) << 4));
        oacc[db] = __builtin_amdgcn_mfma_f32_16x16x32_bf16(pa[kc2], bv, oacc[db], 0, 0, 0);
      }
  }

#pragma unroll
  for (int r = 0; r < 4; r++) {
    float inv = 1.0f / l_run[r];
    int srow = qb * 64 + w * 16 + lhi * 4 + r;
#pragma unroll
    for (int db = 0; db < 8; db++) {
      int dcol = db * 16 + lr;
      float g = (float)sgate[(size_t)((b * 16 + h) * 2048 + srow) * 128 + dcol];
      float ov = oacc[db][r] * inv * g;
      wattn[(size_t)(b * 2048 + srow) * 2048 + h * 128 + dcol] = (bf16)ov;
    }
  }
}

extern "C" void kernel_launch(void* const* d_in, const int* in_sizes, int n_in,
                              void* d_out, int out_size, void* d_ws, size_t ws_size,
                              hipStream_t stream) {
  const float* hidden = (const float*)d_in[0];
  const float* cosT = (const float*)d_in[1];
  const float* sinT = (const float*)d_in[2];
  const float* Wq = (const float*)d_in[3];
  const float* Wk = (const float*)d_in[4];
  const float* Wv = (const float*)d_in[5];
  const float* Wo = (const float*)d_in[6];
  const float* qw = (const float*)d_in[7];
  const float* kw = (const float*)d_in[8];
  const float* Wr = (const float*)d_in[9];
  const float* Wd = (const float*)d_in[10];
  const float* lng = (const float*)d_in[11];
  const float* lnb = (const float*)d_in[12];
  const float* rnn = (const float*)d_in[13];
  float* out = (float*)d_out;

  char* p = (char*)d_ws;
  auto alloc = [&](size_t bytes) { char* r = p; p += (bytes + 255) & ~(size_t)255; return r; };
  bf16* hb    = (bf16*)alloc((size_t)4096 * 2048 * 2);
  bf16* WqT   = (bf16*)alloc((size_t)4096 * 2048 * 2);
  bf16* WkT   = (bf16*)alloc((size_t)512 * 2048 * 2);
  bf16* WvT   = (bf16*)alloc((size_t)512 * 2048 * 2);
  bf16* WrT   = (bf16*)alloc((size_t)128 * 2048 * 2);
  bf16* WoT   = (bf16*)alloc((size_t)2048 * 2048 * 2);
  bf16* qkvb  = (bf16*)alloc((size_t)4096 * 4096 * 2);
  bf16* krawb = (bf16*)alloc((size_t)4096 * 512 * 2);
  bf16* vrawb = (bf16*)alloc((size_t)4096 * 512 * 2);
  bf16* embb  = (bf16*)alloc((size_t)4096 * 128 * 2);
  bf16* maskb = (bf16*)alloc((size_t)4096 * 128 * 2);
  bf16* wqb   = (bf16*)alloc((size_t)2 * 16 * 2048 * 128 * 2);
  bf16* wkb   = (bf16*)alloc((size_t)2 * 4 * 2048 * 128 * 2);
  bf16* wvtb  = (bf16*)alloc((size_t)2 * 4 * 128 * 2048 * 2);
  bf16* sgb   = (bf16*)alloc((size_t)2 * 16 * 2048 * 128 * 2);
  bf16* wab   = (bf16*)alloc((size_t)4096 * 2048 * 2);
  if ((size_t)(p - (char*)d_ws) > ws_size) return;  // needs ~150 MB scratch

  cvt_bf16_k<<<8192, 256, 0, stream>>>(hidden, hb, 4096 * 2048);
  transpose_cvt<<<dim3(4096 / 64, 2048 / 64), 256, 0, stream>>>(Wq, WqT, 2048, 4096);
  transpose_cvt<<<dim3(512 / 64, 2048 / 64), 256, 0, stream>>>(Wk, WkT, 2048, 512);
  transpose_cvt<<<dim3(512 / 64, 2048 / 64), 256, 0, stream>>>(Wv, WvT, 2048, 512);
  transpose_cvt<<<dim3(128 / 64, 2048 / 64), 256, 0, stream>>>(Wr, WrT, 2048, 128);
  transpose_cvt<<<dim3(2048 / 64, 2048 / 64), 256, 0, stream>>>(Wo, WoT, 2048, 2048);

  gemm_bt<bf16><<<32 * 32, 256, 0, stream>>>(hb, WqT, qkvb, 4096, 4096, 2048);
  gemm_bt<bf16><<<32 * 4, 256, 0, stream>>>(hb, WkT, krawb, 4096, 512, 2048);
  gemm_bt<bf16><<<32 * 4, 256, 0, stream>>>(hb, WvT, vrawb, 4096, 512, 2048);
  gemm_bt<bf16><<<32 * 1, 256, 0, stream>>>(hb, WrT, embb, 4096, 128, 2048);

  mask_kernel<<<4096, 128, 0, stream>>>(embb, rnn, lng, lnb, Wd, maskb);
  qgate_kernel<<<65536, 128, 0, stream>>>(qkvb, maskb, qw, cosT, sinT, wqb, sgb);
  k_kernel<<<16384, 128, 0, stream>>>(krawb, maskb, kw, cosT, sinT, wkb);
  vt_kernel<<<512, 256, 0, stream>>>(vrawb, wvtb);

  attn_kernel<<<1024, 256, 0, stream>>>(wqb, wkb, wvtb, sgb, wab);

  gemm_bt<float><<<16 * 32, 256, 0, stream>>>(wab, WoT, out, 4096, 2048, 2048);
}

// Round 2
// 395.567 us; speedup vs baseline: 1.8327x; 1.8327x over previous
//
#include <hip/hip_runtime.h>
#include <math.h>

typedef __bf16 bf16;
typedef bf16 bf16x8 __attribute__((ext_vector_type(8)));
typedef bf16 bf16x4 __attribute__((ext_vector_type(4)));
typedef float f32x4 __attribute__((ext_vector_type(4)));

#define BB 2
#define SS 2048
#define HIDN 2048
#define NH 16
#define NKV 4
#define DD 128
#define NROT 64

__device__ __forceinline__ float waveAllReduceSum(float v) {
#pragma unroll
  for (int o = 1; o < 64; o <<= 1) v += __shfl_xor(v, o, 64);
  return v;
}

// async global->LDS, 16B per lane; LDS dest must be linear (base + lane*16)
__device__ __forceinline__ void gload16(const bf16* g, bf16* l) {
  __builtin_amdgcn_global_load_lds((const __attribute__((address_space(1))) void*)g,
                                   (__attribute__((address_space(3))) void*)l, 16, 0, 0);
}

// ---------------- convert f32 -> bf16 ----------------
__global__ __launch_bounds__(256) void cvt_bf16_k(const float* __restrict__ in,
                                                  bf16* __restrict__ out, int n) {
  int i = (blockIdx.x * 256 + threadIdx.x) * 4;
  if (i + 3 < n) {
    float4 v = *reinterpret_cast<const float4*>(in + i);
    bf16x4 o = {(bf16)v.x, (bf16)v.y, (bf16)v.z, (bf16)v.w};
    *reinterpret_cast<bf16x4*>(out + i) = o;
  }
}

// ---------------- transpose + convert: W (K x N) f32 -> WT (N x K) bf16 ----------------
__global__ __launch_bounds__(256) void transpose_cvt(const float* __restrict__ W,
                                                     bf16* __restrict__ WT, int K, int N) {
  __shared__ bf16 tile[64][72];
  int n0 = blockIdx.x * 64, k0 = blockIdx.y * 64;
  int tx = threadIdx.x & 63, ty = threadIdx.x >> 6;
#pragma unroll
  for (int i = 0; i < 16; i++) {
    int k = ty + i * 4;
    tile[k][tx] = (bf16)W[(size_t)(k0 + k) * N + n0 + tx];
  }
  __syncthreads();
#pragma unroll
  for (int i = 0; i < 16; i++) {
    int n = ty + i * 4;
    WT[(size_t)(n0 + n) * K + k0 + tx] = tile[tx][n];
  }
}

// ---------------- GEMM: C(MxN) = A(MxK) @ Bt(NxK)^T, bf16 in, CT out ----------------
// 128x128 tile, BK=64, 4 waves (2x2 of 64x64), mfma 16x16x32 bf16.
// global_load_lds staging: linear LDS dest, pre-swizzled global source (slot ^= row&7).
template <typename CT>
__global__ __launch_bounds__(256) void gemm_bt(const bf16* __restrict__ A,
                                               const bf16* __restrict__ Bt,
                                               CT* __restrict__ C, int M, int N, int K) {
  __shared__ bf16 lA[128 * 64];
  __shared__ bf16 lB[128 * 64];
  const int nbx = N >> 7;
  int bx = blockIdx.x % nbx, by = blockIdx.x / nbx;
  const int t = threadIdx.x;
  const int l = t & 63, w = t >> 6;
  const int wr = w >> 1, wc = w & 1;
  const int lr = l & 15, lhi = l >> 4;

  f32x4 acc[4][4];
#pragma unroll
  for (int m = 0; m < 4; m++)
#pragma unroll
    for (int n = 0; n < 4; n++) acc[m][n] = f32x4{0.f, 0.f, 0.f, 0.f};

  const int rowA0 = by * 128, rowB0 = bx * 128;
  const int nkt = K >> 6;
  for (int kt = 0; kt < nkt; ++kt) {
    __syncthreads();
#pragma unroll
    for (int it = 0; it < 4; ++it) {
      int slot = it * 256 + t;
      int row = slot >> 3, sl = slot & 7;
      gload16(A + (size_t)(rowA0 + row) * K + kt * 64 + ((sl ^ (row & 7)) << 3), lA + slot * 8);
      gload16(Bt + (size_t)(rowB0 + row) * K + kt * 64 + ((sl ^ (row & 7)) << 3), lB + slot * 8);
    }
    __syncthreads();
#pragma unroll
    for (int kc = 0; kc < 2; ++kc) {
      bf16x8 af[4], bg[4];
#pragma unroll
      for (int m = 0; m < 4; m++) {
        int row = wr * 64 + m * 16 + lr;
        af[m] = *reinterpret_cast<const bf16x8*>((char*)lA + row * 128 + (((kc * 4 + lhi) ^ (row & 7)) << 4));
      }
#pragma unroll
      for (int n = 0; n < 4; n++) {
        int row = wc * 64 + n * 16 + lr;
        bg[n] = *reinterpret_cast<const bf16x8*>((char*)lB + row * 128 + (((kc * 4 + lhi) ^ (row & 7)) << 4));
      }
      __builtin_amdgcn_s_setprio(1);
#pragma unroll
      for (int m = 0; m < 4; m++)
#pragma unroll
        for (int n = 0; n < 4; n++)
          acc[m][n] = __builtin_amdgcn_mfma_f32_16x16x32_bf16(af[m], bg[n], acc[m][n], 0, 0, 0);
      __builtin_amdgcn_s_setprio(0);
    }
  }
#pragma unroll
  for (int m = 0; m < 4; m++)
#pragma unroll
    for (int n = 0; n < 4; n++)
#pragma unroll
      for (int r = 0; r < 4; r++) {
        int grow = rowA0 + wr * 64 + m * 16 + lhi * 4 + r;
        int gcol = rowB0 + wc * 64 + n * 16 + lr;
        C[(size_t)grow * N + gcol] = (CT)acc[m][n][r];
      }
}

// ---------------- Threefry-2x32 (JAX), key (0,42) -> gumbel ----------------
__device__ __forceinline__ unsigned rotl32(unsigned x, int r) { return (x << r) | (x >> (32 - r)); }

__device__ __forceinline__ float gumbel42(unsigned i) {
  const unsigned half = (unsigned)(BB * SS * DD) / 2u;  // 262144
  unsigned x0, x1;
  int word;
  if (i < half) { x0 = i; x1 = i + half; word = 0; }
  else          { x0 = i - half; x1 = i; word = 1; }
  const unsigned k0 = 0u, k1 = 42u;
  const unsigned k2 = k0 ^ k1 ^ 0x1BD11BDAu;
  x0 += k0; x1 += k1;
#define TF_R(r) { x0 += x1; x1 = rotl32(x1, r); x1 ^= x0; }
  TF_R(13) TF_R(15) TF_R(26) TF_R(6)
  x0 += k1; x1 += k2 + 1u;
  TF_R(17) TF_R(29) TF_R(16) TF_R(24)
  x0 += k2; x1 += k0 + 2u;
  TF_R(13) TF_R(15) TF_R(26) TF_R(6)
  x0 += k0; x1 += k1 + 3u;
  TF_R(17) TF_R(29) TF_R(16) TF_R(24)
  x0 += k1; x1 += k2 + 4u;
  TF_R(13) TF_R(15) TF_R(26) TF_R(6)
  x0 += k2; x1 += k0 + 5u;
#undef TF_R
  unsigned bits = word ? x1 : x0;
  float u = __uint_as_float((bits >> 9) | 0x3f800000u) - 1.0f;
  float ex = -log1pf(-u);
  return -logf(ex);
}

// ---------------- mask kernel: LN -> gelu -> @Wd -> +gumbel -> sigmoid -> round ----------------
__global__ __launch_bounds__(128) void mask_kernel(const bf16* __restrict__ embb,
                                                   const float* __restrict__ rnn,
                                                   const float* __restrict__ lng,
                                                   const float* __restrict__ lnb,
                                                   const float* __restrict__ Wd,
                                                   bf16* __restrict__ maskb) {
  int row = blockIdx.x;
  int t = threadIdx.x;
  int l = t & 63, w = t >> 6;
  __shared__ float redm[2], redv[2], gsh[128];
  float e = (float)embb[(size_t)row * 128 + t] + rnn[t];
  float s1 = waveAllReduceSum(e);
  if (l == 0) redm[w] = s1;
  __syncthreads();
  float mu = (redm[0] + redm[1]) * (1.0f / 128.0f);
  float dv = (e - mu) * (e - mu);
  float s2 = waveAllReduceSum(dv);
  if (l == 0) redv[w] = s2;
  __syncthreads();
  float var = (redv[0] + redv[1]) * (1.0f / 128.0f);
  float ln = (e - mu) * rsqrtf(var + 1e-5f) * lng[t] + lnb[t];
  float g = 0.5f * ln * (1.0f + erff(ln * 0.7071067811865475f));
  gsh[t] = g;
  __syncthreads();
  float logit = 0.f;
#pragma unroll 8
  for (int e2 = 0; e2 < 128; e2++) logit += gsh[e2] * Wd[e2 * 128 + t];
  float gum = gumbel42((unsigned)(row * 128 + t));
  float x = (logit + gum + 3.0f) * 2.5f;
  float y = 1.0f / (1.0f + expf(-x));
  maskb[(size_t)row * 128 + t] = (bf16)rintf(y);
}

// ---------------- q/gate: RMSNorm, mask, RoPE, scale ----------------
__global__ __launch_bounds__(128) void qgate_kernel(const bf16* __restrict__ qkv,
                                                    const bf16* __restrict__ maskb,
                                                    const float* __restrict__ qw,
                                                    const float* __restrict__ cosT,
                                                    const float* __restrict__ sinT,
                                                    bf16* __restrict__ wq,
                                                    bf16* __restrict__ sgate) {
  int idx = blockIdx.x;
  int h = idx & 15;
  int row = idx >> 4;
  int b = row >> 11, s = row & 2047;
  int d = threadIdx.x;
  int l = d & 63, w = d >> 6;
  __shared__ float sq[128];
  __shared__ float red2[2];
  float qv = (float)qkv[(size_t)row * 4096 + h * 256 + d];
  float gv = (float)qkv[(size_t)row * 4096 + h * 256 + 128 + d];
  float ss = waveAllReduceSum(qv * qv);
  if (l == 0) red2[w] = ss;
  __syncthreads();
  float ms = (red2[0] + red2[1]) * (1.0f / 128.0f);
  float qn = qv * rsqrtf(ms + 1e-6f) * (1.0f + qw[d]);
  float qm = qn * (float)maskb[(size_t)row * 128 + d];
  sq[d] = qm;
  __syncthreads();
  float outv;
  if (d < 64) {
    float c = cosT[(size_t)row * 64 + d];
    float si = sinT[(size_t)row * 64 + d];
    float other = (d < 32) ? -sq[d + 32] : sq[d - 32];
    outv = qm * c + other * si;
  } else outv = qm;
  outv *= 0.08838834764831845f;
  size_t o = ((size_t)((b * 16 + h) * 2048 + s)) * 128 + d;
  wq[o] = (bf16)outv;
  sgate[o] = (bf16)(1.0f / (1.0f + expf(-gv)));
}

// ---------------- k: RMSNorm, mask, RoPE ----------------
__global__ __launch_bounds__(128) void k_kernel(const bf16* __restrict__ kraw,
                                                const bf16* __restrict__ maskb,
                                                const float* __restrict__ kw,
                                                const float* __restrict__ cosT,
                                                const float* __restrict__ sinT,
                                                bf16* __restrict__ wk) {
  int idx = blockIdx.x;
  int kv = idx & 3;
  int row = idx >> 2;
  int b = row >> 11, s = row & 2047;
  int d = threadIdx.x;
  int l = d & 63, w = d >> 6;
  __shared__ float sk[128];
  __shared__ float red2[2];
  float kval = (float)kraw[(size_t)row * 512 + kv * 128 + d];
  float ss = waveAllReduceSum(kval * kval);
  if (l == 0) red2[w] = ss;
  __syncthreads();
  float ms = (red2[0] + red2[1]) * (1.0f / 128.0f);
  float kn = kval * rsqrtf(ms + 1e-6f) * (1.0f + kw[d]);
  float km = kn * (float)maskb[(size_t)row * 128 + d];
  sk[d] = km;
  __syncthreads();
  float outv;
  if (d < 64) {
    float c = cosT[(size_t)row * 64 + d];
    float si = sinT[(size_t)row * 64 + d];
    float other = (d < 32) ? -sk[d + 32] : sk[d - 32];
    outv = km * c + other * si;
  } else outv = km;
  wk[((size_t)((b * 4 + kv) * 2048 + s)) * 128 + d] = (bf16)outv;
}

// ---------------- v transpose: vraw[b,s,kv*128+d] -> wvt[b,kv,d,s] ----------------
__global__ __launch_bounds__(256) void vt_kernel(const bf16* __restrict__ vraw,
                                                 bf16* __restrict__ wvt) {
  int dt = blockIdx.x & 1;
  int st = (blockIdx.x >> 1) & 31;
  int bkv = blockIdx.x >> 6;
  int b = bkv >> 2, kv = bkv & 3;
  __shared__ bf16 tl[64][72];
  int tx = threadIdx.x & 63, ty = threadIdx.x >> 6;
  int s0 = st * 64, d0 = dt * 64;
#pragma unroll
  for (int i = 0; i < 16; i++) {
    int srow = ty + i * 4;
    tl[srow][tx] = vraw[(size_t)(b * 2048 + s0 + srow) * 512 + kv * 128 + d0 + tx];
  }
  __syncthreads();
#pragma unroll
  for (int i = 0; i < 16; i++) {
    int drow = ty + i * 4;
    wvt[(size_t)((b * 4 + kv) * 128 + d0 + drow) * 2048 + s0 + tx] = tl[tx][drow];
  }
}

// ---------------- flash attention v2: swapped QK^T, paired q-tiles, gload_lds staging ----------------
__global__ __launch_bounds__(256) void attn_kernel(const bf16* __restrict__ wq,
                                                   const bf16* __restrict__ wk,
                                                   const bf16* __restrict__ wvt,
                                                   const bf16* __restrict__ sgate,
                                                   bf16* __restrict__ wattn) {
  __shared__ bf16 lK[64 * 128];   // [kv 64][d 128], source-swizzled
  __shared__ bf16 lV[128 * 64];   // [d 128][kv 64], source-swizzled
  __shared__ bf16 lP[4][16 * 64]; // per-wave P[q 16][k 64], write-swizzled
  int pair = blockIdx.x & 15;
  int bh = blockIdx.x >> 4;
  int b = bh >> 4, h = bh & 15, kvh = h >> 2;
  int t = threadIdx.x, l = t & 63, w = t >> 6;
  int lr = l & 15, lhi = l >> 4;

  const bf16* kbase = wk + (size_t)((b * 4 + kvh) * 2048) * 128;
  const bf16* vbase = wvt + (size_t)((b * 4 + kvh) * 128) * 2048;
  char* pb = (char*)(&lP[w][0]);

  for (int half = 0; half < 2; ++half) {
    int qb = half ? (31 - pair) : pair;
    const bf16* qbase = wq + (size_t)((b * 16 + h) * 2048 + qb * 64 + w * 16) * 128;
    bf16x8 aq[4];
#pragma unroll
    for (int kc = 0; kc < 4; kc++)
      aq[kc] = *reinterpret_cast<const bf16x8*>(qbase + (size_t)lr * 128 + kc * 32 + lhi * 8);

    f32x4 oacc[8];
#pragma unroll
    for (int db = 0; db < 8; db++) oacc[db] = f32x4{0.f, 0.f, 0.f, 0.f};
    float m_run = -3.0e38f, l_run = 0.f;
    int qrow_g = qb * 64 + w * 16 + lr;  // this lane's q row

    for (int tt = 0; tt <= qb; ++tt) {
      __syncthreads();
#pragma unroll
      for (int it = 0; it < 4; ++it) {
        int slot = it * 256 + t;
        int row = slot >> 4, sl = slot & 15;
        gload16(kbase + (size_t)(tt * 64 + row) * 128 + ((sl ^ (row & 7)) << 3), (bf16*)lK + slot * 8);
        int row2 = slot >> 3, sl2 = slot & 7;
        gload16(vbase + (size_t)row2 * 2048 + tt * 64 + ((sl2 ^ (row2 & 7)) << 3), (bf16*)lV + slot * 8);
      }
      __syncthreads();

      // swapped QK^T: sacc[j] = mfma(K_j, Q) -> S[k local][q = lr]
      f32x4 sacc[4];
#pragma unroll
      for (int j = 0; j < 4; j++) sacc[j] = f32x4{0.f, 0.f, 0.f, 0.f};
      __builtin_amdgcn_s_setprio(1);
#pragma unroll
      for (int kc = 0; kc < 4; kc++)
#pragma unroll
        for (int j = 0; j < 4; j++) {
          int row = j * 16 + lr;
          bf16x8 ak = *reinterpret_cast<const bf16x8*>((char*)lK + row * 256 + (((kc * 4 + lhi) ^ (row & 7)) << 4));
          sacc[j] = __builtin_amdgcn_mfma_f32_16x16x32_bf16(ak, aq[kc], sacc[j], 0, 0, 0);
        }
      __builtin_amdgcn_s_setprio(0);

      if (tt == qb) {  // diagonal tile: causal mask, lane-local
#pragma unroll
        for (int j = 0; j < 4; j++)
#pragma unroll
          for (int r = 0; r < 4; r++) {
            int kg = tt * 64 + j * 16 + lhi * 4 + r;
            if (kg > qrow_g) sacc[j][r] = -1e30f;
          }
      }

      // lane-local row stats for q = lr (tree max over 16 values)
      float m0 = fmaxf(fmaxf(sacc[0][0], sacc[0][1]), fmaxf(sacc[0][2], sacc[0][3]));
      float m1 = fmaxf(fmaxf(sacc[1][0], sacc[1][1]), fmaxf(sacc[1][2], sacc[1][3]));
      float m2 = fmaxf(fmaxf(sacc[2][0], sacc[2][1]), fmaxf(sacc[2][2], sacc[2][3]));
      float m3 = fmaxf(fmaxf(sacc[3][0], sacc[3][1]), fmaxf(sacc[3][2], sacc[3][3]));
      float mx = fmaxf(fmaxf(m0, m1), fmaxf(m2, m3));
      mx = fmaxf(mx, __shfl_xor(mx, 16, 64));
      mx = fmaxf(mx, __shfl_xor(mx, 32, 64));
      float mnew = fmaxf(m_run, mx);
      float p[4][4];
      float rs = 0.f;
#pragma unroll
      for (int j = 0; j < 4; j++) {
        float s0 = 0.f;
#pragma unroll
        for (int r = 0; r < 4; r++) {
          float pv = __expf(sacc[j][r] - mnew);
          p[j][r] = pv;
          s0 += pv;
        }
        rs += s0;
      }
      rs += __shfl_xor(rs, 16, 64);
      rs += __shfl_xor(rs, 32, 64);
      float corr = __expf(m_run - mnew);
      l_run = l_run * corr + rs;
      m_run = mnew;

      // broadcast corr to output layout (q = lhi*4+r) and rescale O
      float corr_o[4];
#pragma unroll
      for (int r = 0; r < 4; r++) corr_o[r] = __shfl(corr, lhi * 4 + r, 64);
#pragma unroll
      for (int db = 0; db < 8; db++)
#pragma unroll
        for (int r = 0; r < 4; r++) oacc[db][r] *= corr_o[r];

      // write P[q=lr][k] to per-wave LDS (4x 8B chunks, XOR-swizzled)
#pragma unroll
      for (int j = 0; j < 4; j++) {
        bf16x4 p4 = {(bf16)p[j][0], (bf16)p[j][1], (bf16)p[j][2], (bf16)p[j][3]};
        *reinterpret_cast<bf16x4*>(pb + lr * 128 + ((j * 32 + lhi * 8) ^ ((lr & 7) << 4))) = p4;
      }
      // read P as PV A-fragments
      bf16x8 pa[2];
#pragma unroll
      for (int kc2 = 0; kc2 < 2; kc2++)
        pa[kc2] = *reinterpret_cast<const bf16x8*>(pb + lr * 128 + ((kc2 * 64 + lhi * 16) ^ ((lr & 7) << 4)));
      __builtin_amdgcn_s_setprio(1);
#pragma unroll
      for (int kc2 = 0; kc2 < 2; kc2++)
#pragma unroll
        for (int db = 0; db < 8; db++) {
          int row = db * 16 + lr;
          bf16x8 bv = *reinterpret_cast<const bf16x8*>((char*)lV + row * 128 + (((kc2 * 4 + lhi) ^ (row & 7)) << 4));
          oacc[db] = __builtin_amdgcn_mfma_f32_16x16x32_bf16(pa[kc2], bv, oacc[db], 0, 0, 0);
        }
      __builtin_amdgcn_s_setprio(0);
    }

    // epilogue: fetch l_run for output-layout rows via shfl, fuse *sigmoid(gate)
    float linv[4];
#pragma unroll
    for (int r = 0; r < 4; r++) linv[r] = 1.0f / __shfl(l_run, lhi * 4 + r, 64);
#pragma unroll
    for (int r = 0; r < 4; r++) {
      int srow = qb * 64 + w * 16 + lhi * 4 + r;
#pragma unroll
      for (int db = 0; db < 8; db++) {
        int dcol = db * 16 + lr;
        float g = (float)sgate[(size_t)((b * 16 + h) * 2048 + srow) * 128 + dcol];
        float ov = oacc[db][r] * linv[r] * g;
        wattn[(size_t)(b * 2048 + srow) * 2048 + h * 128 + dcol] = (bf16)ov;
      }
    }
  }
}

extern "C" void kernel_launch(void* const* d_in, const int* in_sizes, int n_in,
                              void* d_out, int out_size, void* d_ws, size_t ws_size,
                              hipStream_t stream) {
  const float* hidden = (const float*)d_in[0];
  const float* cosT = (const float*)d_in[1];
  const float* sinT = (const float*)d_in[2];
  const float* Wq = (const float*)d_in[3];
  const float* Wk = (const float*)d_in[4];
  const float* Wv = (const float*)d_in[5];
  const float* Wo = (const float*)d_in[6];
  const float* qw = (const float*)d_in[7];
  const float* kw = (const float*)d_in[8];
  const float* Wr = (const float*)d_in[9];
  const float* Wd = (const float*)d_in[10];
  const float* lng = (const float*)d_in[11];
  const float* lnb = (const float*)d_in[12];
  const float* rnn = (const float*)d_in[13];
  float* out = (float*)d_out;

  char* p = (char*)d_ws;
  auto alloc = [&](size_t bytes) { char* r = p; p += (bytes + 255) & ~(size_t)255; return r; };
  bf16* hb    = (bf16*)alloc((size_t)4096 * 2048 * 2);
  bf16* WqT   = (bf16*)alloc((size_t)4096 * 2048 * 2);
  bf16* WkT   = (bf16*)alloc((size_t)512 * 2048 * 2);
  bf16* WvT   = (bf16*)alloc((size_t)512 * 2048 * 2);
  bf16* WrT   = (bf16*)alloc((size_t)128 * 2048 * 2);
  bf16* WoT   = (bf16*)alloc((size_t)2048 * 2048 * 2);
  bf16* qkvb  = (bf16*)alloc((size_t)4096 * 4096 * 2);
  bf16* krawb = (bf16*)alloc((size_t)4096 * 512 * 2);
  bf16* vrawb = (bf16*)alloc((size_t)4096 * 512 * 2);
  bf16* embb  = (bf16*)alloc((size_t)4096 * 128 * 2);
  bf16* maskb = (bf16*)alloc((size_t)4096 * 128 * 2);
  bf16* wqb   = (bf16*)alloc((size_t)2 * 16 * 2048 * 128 * 2);
  bf16* wkb   = (bf16*)alloc((size_t)2 * 4 * 2048 * 128 * 2);
  bf16* wvtb  = (bf16*)alloc((size_t)2 * 4 * 128 * 2048 * 2);
  bf16* sgb   = (bf16*)alloc((size_t)2 * 16 * 2048 * 128 * 2);
  bf16* wab   = (bf16*)alloc((size_t)4096 * 2048 * 2);
  if ((size_t)(p - (char*)d_ws) > ws_size) return;

  cvt_bf16_k<<<8192, 256, 0, stream>>>(hidden, hb, 4096 * 2048);
  transpose_cvt<<<dim3(4096 / 64, 2048 / 64), 256, 0, stream>>>(Wq, WqT, 2048, 4096);
  transpose_cvt<<<dim3(512 / 64, 2048 / 64), 256, 0, stream>>>(Wk, WkT, 2048, 512);
  transpose_cvt<<<dim3(512 / 64, 2048 / 64), 256, 0, stream>>>(Wv, WvT, 2048, 512);
  transpose_cvt<<<dim3(128 / 64, 2048 / 64), 256, 0, stream>>>(Wr, WrT, 2048, 128);
  transpose_cvt<<<dim3(2048 / 64, 2048 / 64), 256, 0, stream>>>(Wo, WoT, 2048, 2048);

  gemm_bt<bf16><<<32 * 32, 256, 0, stream>>>(hb, WqT, qkvb, 4096, 4096, 2048);
  gemm_bt<bf16><<<32 * 4, 256, 0, stream>>>(hb, WkT, krawb, 4096, 512, 2048);
  gemm_bt<bf16><<<32 * 4, 256, 0, stream>>>(hb, WvT, vrawb, 4096, 512, 2048);
  gemm_bt<bf16><<<32 * 1, 256, 0, stream>>>(hb, WrT, embb, 4096, 128, 2048);

  mask_kernel<<<4096, 128, 0, stream>>>(embb, rnn, lng, lnb, Wd, maskb);
  qgate_kernel<<<65536, 128, 0, stream>>>(qkvb, maskb, qw, cosT, sinT, wqb, sgb);
  k_kernel<<<16384, 128, 0, stream>>>(krawb, maskb, kw, cosT, sinT, wkb);
  vt_kernel<<<512, 256, 0, stream>>>(vrawb, wvtb);

  attn_kernel<<<512, 256, 0, stream>>>(wqb, wkb, wvtb, sgb, wab);

  gemm_bt<float><<<16 * 32, 256, 0, stream>>>(wab, WoT, out, 4096, 2048, 2048);
}

// Round 3
// 286.215 us; speedup vs baseline: 2.5329x; 1.3821x over previous
//
#include <hip/hip_runtime.h>
#include <math.h>

typedef __bf16 bf16;
typedef bf16 bf16x8 __attribute__((ext_vector_type(8)));
typedef bf16 bf16x4 __attribute__((ext_vector_type(4)));
typedef float f32x4 __attribute__((ext_vector_type(4)));

#define BB 2
#define SS 2048
#define HIDN 2048
#define NH 16
#define NKV 4
#define DD 128
#define NROT 64
#define NPROJ 5248  // 4096 q/gate + 512 k + 512 v + 128 emb

__device__ __forceinline__ float waveAllReduceSum(float v) {
#pragma unroll
  for (int o = 1; o < 64; o <<= 1) v += __shfl_xor(v, o, 64);
  return v;
}

// bijective XCD swizzle; requires nwg % 8 == 0
__device__ __forceinline__ int xcd_swz(int orig, int nwg) {
  return (orig & 7) * (nwg >> 3) + (orig >> 3);
}

// async global->LDS, 16B per lane; LDS dest must be linear (base + lane*16)
__device__ __forceinline__ void gload16(const bf16* g, bf16* l) {
  __builtin_amdgcn_global_load_lds((const __attribute__((address_space(1))) void*)g,
                                   (__attribute__((address_space(3))) void*)l, 16, 0, 0);
}

// ---------------- convert f32 -> bf16 ----------------
__global__ __launch_bounds__(256) void cvt_bf16_k(const float* __restrict__ in,
                                                  bf16* __restrict__ out, int n) {
  int i = (blockIdx.x * 256 + threadIdx.x) * 4;
  if (i + 3 < n) {
    float4 v = *reinterpret_cast<const float4*>(in + i);
    bf16x4 o = {(bf16)v.x, (bf16)v.y, (bf16)v.z, (bf16)v.w};
    *reinterpret_cast<bf16x4*>(out + i) = o;
  }
}

// ---------------- transpose + convert: W (K x N) f32 -> WT (rowOff+N x K) bf16 ----------------
__global__ __launch_bounds__(256) void transpose_cvt(const float* __restrict__ W,
                                                     bf16* __restrict__ WT, int K, int N,
                                                     int rowOff) {
  __shared__ bf16 tile[64][72];
  int n0 = blockIdx.x * 64, k0 = blockIdx.y * 64;
  int tx = threadIdx.x & 63, ty = threadIdx.x >> 6;
#pragma unroll
  for (int i = 0; i < 16; i++) {
    int k = ty + i * 4;
    tile[k][tx] = (bf16)W[(size_t)(k0 + k) * N + n0 + tx];
  }
  __syncthreads();
#pragma unroll
  for (int i = 0; i < 16; i++) {
    int n = ty + i * 4;
    WT[(size_t)(rowOff + n0 + n) * K + k0 + tx] = tile[tx][n];
  }
}

// ---------------- GEMM: C(MxN) = A(MxK) @ Bt(NxK)^T, bf16 in, CT out ----------------
template <typename CT>
__global__ __launch_bounds__(256) void gemm_bt(const bf16* __restrict__ A,
                                               const bf16* __restrict__ Bt,
                                               CT* __restrict__ C, int M, int N, int K) {
  __shared__ bf16 lA[128 * 64];
  __shared__ bf16 lB[128 * 64];
  const int nbx = N >> 7;
  int wg = xcd_swz(blockIdx.x, gridDim.x);
  int bx = wg % nbx, by = wg / nbx;
  const int t = threadIdx.x;
  const int l = t & 63, w = t >> 6;
  const int wr = w >> 1, wc = w & 1;
  const int lr = l & 15, lhi = l >> 4;

  f32x4 acc[4][4];
#pragma unroll
  for (int m = 0; m < 4; m++)
#pragma unroll
    for (int n = 0; n < 4; n++) acc[m][n] = f32x4{0.f, 0.f, 0.f, 0.f};

  const int rowA0 = by * 128, rowB0 = bx * 128;
  const int nkt = K >> 6;
  for (int kt = 0; kt < nkt; ++kt) {
    __syncthreads();
#pragma unroll
    for (int it = 0; it < 4; ++it) {
      int slot = it * 256 + t;
      int row = slot >> 3, sl = slot & 7;
      gload16(A + (size_t)(rowA0 + row) * K + kt * 64 + ((sl ^ (row & 7)) << 3), lA + slot * 8);
      gload16(Bt + (size_t)(rowB0 + row) * K + kt * 64 + ((sl ^ (row & 7)) << 3), lB + slot * 8);
    }
    __syncthreads();
#pragma unroll
    for (int kc = 0; kc < 2; ++kc) {
      bf16x8 af[4], bg[4];
#pragma unroll
      for (int m = 0; m < 4; m++) {
        int row = wr * 64 + m * 16 + lr;
        af[m] = *reinterpret_cast<const bf16x8*>((char*)lA + row * 128 + (((kc * 4 + lhi) ^ (row & 7)) << 4));
      }
#pragma unroll
      for (int n = 0; n < 4; n++) {
        int row = wc * 64 + n * 16 + lr;
        bg[n] = *reinterpret_cast<const bf16x8*>((char*)lB + row * 128 + (((kc * 4 + lhi) ^ (row & 7)) << 4));
      }
      __builtin_amdgcn_s_setprio(1);
#pragma unroll
      for (int m = 0; m < 4; m++)
#pragma unroll
        for (int n = 0; n < 4; n++)
          acc[m][n] = __builtin_amdgcn_mfma_f32_16x16x32_bf16(af[m], bg[n], acc[m][n], 0, 0, 0);
      __builtin_amdgcn_s_setprio(0);
    }
  }
#pragma unroll
  for (int m = 0; m < 4; m++)
#pragma unroll
    for (int n = 0; n < 4; n++)
#pragma unroll
      for (int r = 0; r < 4; r++) {
        int grow = rowA0 + wr * 64 + m * 16 + lhi * 4 + r;
        int gcol = rowB0 + wc * 64 + n * 16 + lr;
        C[(size_t)grow * N + gcol] = (CT)acc[m][n][r];
      }
}

// ---------------- Threefry-2x32 (JAX), key (0,42) -> gumbel ----------------
__device__ __forceinline__ unsigned rotl32(unsigned x, int r) { return (x << r) | (x >> (32 - r)); }

__device__ __forceinline__ float gumbel42(unsigned i) {
  const unsigned half = (unsigned)(BB * SS * DD) / 2u;  // 262144
  unsigned x0, x1;
  int word;
  if (i < half) { x0 = i; x1 = i + half; word = 0; }
  else          { x0 = i - half; x1 = i; word = 1; }
  const unsigned k0 = 0u, k1 = 42u;
  const unsigned k2 = k0 ^ k1 ^ 0x1BD11BDAu;
  x0 += k0; x1 += k1;
#define TF_R(r) { x0 += x1; x1 = rotl32(x1, r); x1 ^= x0; }
  TF_R(13) TF_R(15) TF_R(26) TF_R(6)
  x0 += k1; x1 += k2 + 1u;
  TF_R(17) TF_R(29) TF_R(16) TF_R(24)
  x0 += k2; x1 += k0 + 2u;
  TF_R(13) TF_R(15) TF_R(26) TF_R(6)
  x0 += k0; x1 += k1 + 3u;
  TF_R(17) TF_R(29) TF_R(16) TF_R(24)
  x0 += k1; x1 += k2 + 4u;
  TF_R(13) TF_R(15) TF_R(26) TF_R(6)
  x0 += k2; x1 += k0 + 5u;
#undef TF_R
  unsigned bits = word ? x1 : x0;
  float u = __uint_as_float((bits >> 9) | 0x3f800000u) - 1.0f;
  float ex = -log1pf(-u);
  return -logf(ex);
}

// ---------------- mask kernel: LN -> gelu -> @Wd -> +gumbel -> sigmoid -> round ----------------
__global__ __launch_bounds__(128) void mask_kernel(const bf16* __restrict__ qkva,
                                                   const float* __restrict__ rnn,
                                                   const float* __restrict__ lng,
                                                   const float* __restrict__ lnb,
                                                   const float* __restrict__ Wd,
                                                   bf16* __restrict__ maskb) {
  int row = blockIdx.x;
  int t = threadIdx.x;
  int l = t & 63, w = t >> 6;
  __shared__ float redm[2], redv[2], gsh[128];
  float e = (float)qkva[(size_t)row * NPROJ + 5120 + t] + rnn[t];
  float s1 = waveAllReduceSum(e);
  if (l == 0) redm[w] = s1;
  __syncthreads();
  float mu = (redm[0] + redm[1]) * (1.0f / 128.0f);
  float dv = (e - mu) * (e - mu);
  float s2 = waveAllReduceSum(dv);
  if (l == 0) redv[w] = s2;
  __syncthreads();
  float var = (redv[0] + redv[1]) * (1.0f / 128.0f);
  float ln = (e - mu) * rsqrtf(var + 1e-5f) * lng[t] + lnb[t];
  float g = 0.5f * ln * (1.0f + erff(ln * 0.7071067811865475f));
  gsh[t] = g;
  __syncthreads();
  float logit = 0.f;
#pragma unroll 8
  for (int e2 = 0; e2 < 128; e2++) logit += gsh[e2] * Wd[e2 * 128 + t];
  float gum = gumbel42((unsigned)(row * 128 + t));
  float x = (logit + gum + 3.0f) * 2.5f;
  float y = 1.0f / (1.0f + expf(-x));
  maskb[(size_t)row * 128 + t] = (bf16)rintf(y);
}

// ---------------- q/gate: vectorized RMSNorm+mask+RoPE+scale; 16 lanes/head-row ----------------
__global__ __launch_bounds__(256) void qgate_kernel(const bf16* __restrict__ qkva,
                                                    const bf16* __restrict__ maskb,
                                                    const float* __restrict__ qw,
                                                    const float* __restrict__ cosT,
                                                    const float* __restrict__ sinT,
                                                    bf16* __restrict__ wq,
                                                    bf16* __restrict__ sgate) {
  int t = threadIdx.x;
  int g = t >> 4, ln = t & 15;
  int hr = blockIdx.x * 16 + g;
  int h = hr & 15, row = hr >> 4;
  int b = row >> 11, s = row & 2047;
  const bf16* qp = qkva + (size_t)row * NPROJ + h * 256 + ln * 8;
  bf16x8 q8 = *reinterpret_cast<const bf16x8*>(qp);
  bf16x8 g8 = *reinterpret_cast<const bf16x8*>(qp + 128);
  bf16x8 m8 = *reinterpret_cast<const bf16x8*>(maskb + (size_t)row * 128 + ln * 8);
  float qf[8], ss = 0.f;
#pragma unroll
  for (int j = 0; j < 8; j++) { qf[j] = (float)q8[j]; ss += qf[j] * qf[j]; }
#pragma unroll
  for (int o = 1; o < 16; o <<= 1) ss += __shfl_xor(ss, o, 16);
  float rinv = rsqrtf(ss * (1.0f / 128.0f) + 1e-6f);
  alignas(16) float wv[8];
  const float4* qw4 = reinterpret_cast<const float4*>(qw);
  *reinterpret_cast<float4*>(&wv[0]) = qw4[ln * 2];
  *reinterpret_cast<float4*>(&wv[4]) = qw4[ln * 2 + 1];
  float qm[8];
#pragma unroll
  for (int j = 0; j < 8; j++) qm[j] = qf[j] * rinv * (1.0f + wv[j]) * (float)m8[j];
  // RoPE: lanes 0..7 hold d=0..63; partner at lane^4 (d +/- 32)
  alignas(16) float c8[8], s8[8];
  if (ln < 8) {
    const float4* c4 = reinterpret_cast<const float4*>(cosT + (size_t)row * 64);
    const float4* sn4 = reinterpret_cast<const float4*>(sinT + (size_t)row * 64);
    *reinterpret_cast<float4*>(&c8[0]) = c4[ln * 2];
    *reinterpret_cast<float4*>(&c8[4]) = c4[ln * 2 + 1];
    *reinterpret_cast<float4*>(&s8[0]) = sn4[ln * 2];
    *reinterpret_cast<float4*>(&s8[4]) = sn4[ln * 2 + 1];
  }
  float po[8];
#pragma unroll
  for (int j = 0; j < 8; j++) po[j] = __shfl_xor(qm[j], 4, 16);
  bf16x8 oq, og;
#pragma unroll
  for (int j = 0; j < 8; j++) {
    float ov;
    if (ln < 4) ov = qm[j] * c8[j] - po[j] * s8[j];
    else if (ln < 8) ov = qm[j] * c8[j] + po[j] * s8[j];
    else ov = qm[j];
    oq[j] = (bf16)(ov * 0.08838834764831845f);
    og[j] = (bf16)(1.0f / (1.0f + expf(-(float)g8[j])));
  }
  size_t o = ((size_t)((b * 16 + h) * 2048 + s)) * 128 + ln * 8;
  *reinterpret_cast<bf16x8*>(wq + o) = oq;
  *reinterpret_cast<bf16x8*>(sgate + o) = og;
}

// ---------------- k: vectorized RMSNorm+mask+RoPE; 16 lanes/kv-row ----------------
__global__ __launch_bounds__(256) void k_kernel(const bf16* __restrict__ qkva,
                                                const bf16* __restrict__ maskb,
                                                const float* __restrict__ kw,
                                                const float* __restrict__ cosT,
                                                const float* __restrict__ sinT,
                                                bf16* __restrict__ wk) {
  int t = threadIdx.x;
  int g = t >> 4, ln = t & 15;
  int hr = blockIdx.x * 16 + g;
  int kv = hr & 3, row = hr >> 2;
  int b = row >> 11, s = row & 2047;
  const bf16* kp = qkva + (size_t)row * NPROJ + 4096 + kv * 128 + ln * 8;
  bf16x8 k8 = *reinterpret_cast<const bf16x8*>(kp);
  bf16x8 m8 = *reinterpret_cast<const bf16x8*>(maskb + (size_t)row * 128 + ln * 8);
  float kf[8], ss = 0.f;
#pragma unroll
  for (int j = 0; j < 8; j++) { kf[j] = (float)k8[j]; ss += kf[j] * kf[j]; }
#pragma unroll
  for (int o = 1; o < 16; o <<= 1) ss += __shfl_xor(ss, o, 16);
  float rinv = rsqrtf(ss * (1.0f / 128.0f) + 1e-6f);
  alignas(16) float wv[8];
  const float4* kw4 = reinterpret_cast<const float4*>(kw);
  *reinterpret_cast<float4*>(&wv[0]) = kw4[ln * 2];
  *reinterpret_cast<float4*>(&wv[4]) = kw4[ln * 2 + 1];
  float km[8];
#pragma unroll
  for (int j = 0; j < 8; j++) km[j] = kf[j] * rinv * (1.0f + wv[j]) * (float)m8[j];
  alignas(16) float c8[8], s8[8];
  if (ln < 8) {
    const float4* c4 = reinterpret_cast<const float4*>(cosT + (size_t)row * 64);
    const float4* sn4 = reinterpret_cast<const float4*>(sinT + (size_t)row * 64);
    *reinterpret_cast<float4*>(&c8[0]) = c4[ln * 2];
    *reinterpret_cast<float4*>(&c8[4]) = c4[ln * 2 + 1];
    *reinterpret_cast<float4*>(&s8[0]) = sn4[ln * 2];
    *reinterpret_cast<float4*>(&s8[4]) = sn4[ln * 2 + 1];
  }
  float po[8];
#pragma unroll
  for (int j = 0; j < 8; j++) po[j] = __shfl_xor(km[j], 4, 16);
  bf16x8 ok;
#pragma unroll
  for (int j = 0; j < 8; j++) {
    float ov;
    if (ln < 4) ov = km[j] * c8[j] - po[j] * s8[j];
    else if (ln < 8) ov = km[j] * c8[j] + po[j] * s8[j];
    else ov = km[j];
    ok[j] = (bf16)ov;
  }
  *reinterpret_cast<bf16x8*>(wk + ((size_t)((b * 4 + kv) * 2048 + s)) * 128 + ln * 8) = ok;
}

// ---------------- v transpose: qkva[row, 4608+kv*128+d] -> wvt[b,kv,d,s] ----------------
__global__ __launch_bounds__(256) void vt_kernel(const bf16* __restrict__ qkva,
                                                 bf16* __restrict__ wvt) {
  int dt = blockIdx.x & 1;
  int st = (blockIdx.x >> 1) & 31;
  int bkv = blockIdx.x >> 6;
  int b = bkv >> 2, kv = bkv & 3;
  __shared__ bf16 tl[64][72];
  int tx = threadIdx.x & 63, ty = threadIdx.x >> 6;
  int s0 = st * 64, d0 = dt * 64;
#pragma unroll
  for (int i = 0; i < 16; i++) {
    int srow = ty + i * 4;
    tl[srow][tx] = qkva[(size_t)(b * 2048 + s0 + srow) * NPROJ + 4608 + kv * 128 + d0 + tx];
  }
  __syncthreads();
#pragma unroll
  for (int i = 0; i < 16; i++) {
    int drow = ty + i * 4;
    wvt[(size_t)((b * 4 + kv) * 128 + d0 + drow) * 2048 + s0 + tx] = tl[tx][drow];
  }
}

// ---------------- flash attention: swapped QK^T, paired q-tiles, gload_lds staging ----------------
__global__ __launch_bounds__(256) void attn_kernel(const bf16* __restrict__ wq,
                                                   const bf16* __restrict__ wk,
                                                   const bf16* __restrict__ wvt,
                                                   const bf16* __restrict__ sgate,
                                                   bf16* __restrict__ wattn) {
  __shared__ bf16 lK[64 * 128];
  __shared__ bf16 lV[128 * 64];
  __shared__ bf16 lP[4][16 * 64];
  int wg = xcd_swz(blockIdx.x, 512);
  int pair = wg & 15;
  int bh = wg >> 4;
  int b = bh >> 4, h = bh & 15, kvh = h >> 2;
  int t = threadIdx.x, l = t & 63, w = t >> 6;
  int lr = l & 15, lhi = l >> 4;

  const bf16* kbase = wk + (size_t)((b * 4 + kvh) * 2048) * 128;
  const bf16* vbase = wvt + (size_t)((b * 4 + kvh) * 128) * 2048;
  char* pb = (char*)(&lP[w][0]);

  for (int half = 0; half < 2; ++half) {
    int qb = half ? (31 - pair) : pair;
    const bf16* qbase = wq + (size_t)((b * 16 + h) * 2048 + qb * 64 + w * 16) * 128;
    bf16x8 aq[4];
#pragma unroll
    for (int kc = 0; kc < 4; kc++)
      aq[kc] = *reinterpret_cast<const bf16x8*>(qbase + (size_t)lr * 128 + kc * 32 + lhi * 8);

    f32x4 oacc[8];
#pragma unroll
    for (int db = 0; db < 8; db++) oacc[db] = f32x4{0.f, 0.f, 0.f, 0.f};
    float m_run = -3.0e38f, l_run = 0.f;
    int qrow_g = qb * 64 + w * 16 + lr;

    for (int tt = 0; tt <= qb; ++tt) {
      __syncthreads();
#pragma unroll
      for (int it = 0; it < 4; ++it) {
        int slot = it * 256 + t;
        int row = slot >> 4, sl = slot & 15;
        gload16(kbase + (size_t)(tt * 64 + row) * 128 + ((sl ^ (row & 7)) << 3), (bf16*)lK + slot * 8);
        int row2 = slot >> 3, sl2 = slot & 7;
        gload16(vbase + (size_t)row2 * 2048 + tt * 64 + ((sl2 ^ (row2 & 7)) << 3), (bf16*)lV + slot * 8);
      }
      __syncthreads();

      f32x4 sacc[4];
#pragma unroll
      for (int j = 0; j < 4; j++) sacc[j] = f32x4{0.f, 0.f, 0.f, 0.f};
      __builtin_amdgcn_s_setprio(1);
#pragma unroll
      for (int kc = 0; kc < 4; kc++)
#pragma unroll
        for (int j = 0; j < 4; j++) {
          int row = j * 16 + lr;
          bf16x8 ak = *reinterpret_cast<const bf16x8*>((char*)lK + row * 256 + (((kc * 4 + lhi) ^ (row & 7)) << 4));
          sacc[j] = __builtin_amdgcn_mfma_f32_16x16x32_bf16(ak, aq[kc], sacc[j], 0, 0, 0);
        }
      __builtin_amdgcn_s_setprio(0);

      if (tt == qb) {
#pragma unroll
        for (int j = 0; j < 4; j++)
#pragma unroll
          for (int r = 0; r < 4; r++) {
            int kg = tt * 64 + j * 16 + lhi * 4 + r;
            if (kg > qrow_g) sacc[j][r] = -1e30f;
          }
      }

      float m0 = fmaxf(fmaxf(sacc[0][0], sacc[0][1]), fmaxf(sacc[0][2], sacc[0][3]));
      float m1 = fmaxf(fmaxf(sacc[1][0], sacc[1][1]), fmaxf(sacc[1][2], sacc[1][3]));
      float m2 = fmaxf(fmaxf(sacc[2][0], sacc[2][1]), fmaxf(sacc[2][2], sacc[2][3]));
      float m3 = fmaxf(fmaxf(sacc[3][0], sacc[3][1]), fmaxf(sacc[3][2], sacc[3][3]));
      float mx = fmaxf(fmaxf(m0, m1), fmaxf(m2, m3));
      mx = fmaxf(mx, __shfl_xor(mx, 16, 64));
      mx = fmaxf(mx, __shfl_xor(mx, 32, 64));
      float mnew = fmaxf(m_run, mx);
      float p[4][4];
      float rs = 0.f;
#pragma unroll
      for (int j = 0; j < 4; j++) {
        float s0 = 0.f;
#pragma unroll
        for (int r = 0; r < 4; r++) {
          float pv = __expf(sacc[j][r] - mnew);
          p[j][r] = pv;
          s0 += pv;
        }
        rs += s0;
      }
      rs += __shfl_xor(rs, 16, 64);
      rs += __shfl_xor(rs, 32, 64);
      float corr = __expf(m_run - mnew);
      l_run = l_run * corr + rs;
      m_run = mnew;

      float corr_o[4];
#pragma unroll
      for (int r = 0; r < 4; r++) corr_o[r] = __shfl(corr, lhi * 4 + r, 64);
#pragma unroll
      for (int db = 0; db < 8; db++)
#pragma unroll
        for (int r = 0; r < 4; r++) oacc[db][r] *= corr_o[r];

#pragma unroll
      for (int j = 0; j < 4; j++) {
        bf16x4 p4 = {(bf16)p[j][0], (bf16)p[j][1], (bf16)p[j][2], (bf16)p[j][3]};
        *reinterpret_cast<bf16x4*>(pb + lr * 128 + ((j * 32 + lhi * 8) ^ ((lr & 7) << 4))) = p4;
      }
      bf16x8 pa[2];
#pragma unroll
      for (int kc2 = 0; kc2 < 2; kc2++)
        pa[kc2] = *reinterpret_cast<const bf16x8*>(pb + lr * 128 + ((kc2 * 64 + lhi * 16) ^ ((lr & 7) << 4)));
      __builtin_amdgcn_s_setprio(1);
#pragma unroll
      for (int kc2 = 0; kc2 < 2; kc2++)
#pragma unroll
        for (int db = 0; db < 8; db++) {
          int row = db * 16 + lr;
          bf16x8 bv = *reinterpret_cast<const bf16x8*>((char*)lV + row * 128 + (((kc2 * 4 + lhi) ^ (row & 7)) << 4));
          oacc[db] = __builtin_amdgcn_mfma_f32_16x16x32_bf16(pa[kc2], bv, oacc[db], 0, 0, 0);
        }
      __builtin_amdgcn_s_setprio(0);
    }

    float linv[4];
#pragma unroll
    for (int r = 0; r < 4; r++) linv[r] = 1.0f / __shfl(l_run, lhi * 4 + r, 64);
#pragma unroll
    for (int r = 0; r < 4; r++) {
      int srow = qb * 64 + w * 16 + lhi * 4 + r;
#pragma unroll
      for (int db = 0; db < 8; db++) {
        int dcol = db * 16 + lr;
        float g = (float)sgate[(size_t)((b * 16 + h) * 2048 + srow) * 128 + dcol];
        float ov = oacc[db][r] * linv[r] * g;
        wattn[(size_t)(b * 2048 + srow) * 2048 + h * 128 + dcol] = (bf16)ov;
      }
    }
  }
}

extern "C" void kernel_launch(void* const* d_in, const int* in_sizes, int n_in,
                              void* d_out, int out_size, void* d_ws, size_t ws_size,
                              hipStream_t stream) {
  const float* hidden = (const float*)d_in[0];
  const float* cosT = (const float*)d_in[1];
  const float* sinT = (const float*)d_in[2];
  const float* Wq = (const float*)d_in[3];
  const float* Wk = (const float*)d_in[4];
  const float* Wv = (const float*)d_in[5];
  const float* Wo = (const float*)d_in[6];
  const float* qw = (const float*)d_in[7];
  const float* kw = (const float*)d_in[8];
  const float* Wr = (const float*)d_in[9];
  const float* Wd = (const float*)d_in[10];
  const float* lng = (const float*)d_in[11];
  const float* lnb = (const float*)d_in[12];
  const float* rnn = (const float*)d_in[13];
  float* out = (float*)d_out;

  char* p = (char*)d_ws;
  auto alloc = [&](size_t bytes) { char* r = p; p += (bytes + 255) & ~(size_t)255; return r; };
  bf16* hb    = (bf16*)alloc((size_t)4096 * 2048 * 2);
  bf16* WTall = (bf16*)alloc((size_t)NPROJ * 2048 * 2);
  bf16* WoT   = (bf16*)alloc((size_t)2048 * 2048 * 2);
  bf16* qkva  = (bf16*)alloc((size_t)4096 * NPROJ * 2);
  bf16* maskb = (bf16*)alloc((size_t)4096 * 128 * 2);
  bf16* wqb   = (bf16*)alloc((size_t)2 * 16 * 2048 * 128 * 2);
  bf16* wkb   = (bf16*)alloc((size_t)2 * 4 * 2048 * 128 * 2);
  bf16* wvtb  = (bf16*)alloc((size_t)2 * 4 * 128 * 2048 * 2);
  bf16* sgb   = (bf16*)alloc((size_t)2 * 16 * 2048 * 128 * 2);
  bf16* wab   = (bf16*)alloc((size_t)4096 * 2048 * 2);
  if ((size_t)(p - (char*)d_ws) > ws_size) return;

  cvt_bf16_k<<<8192, 256, 0, stream>>>(hidden, hb, 4096 * 2048);
  transpose_cvt<<<dim3(64, 32), 256, 0, stream>>>(Wq, WTall, 2048, 4096, 0);
  transpose_cvt<<<dim3(8, 32), 256, 0, stream>>>(Wk, WTall, 2048, 512, 4096);
  transpose_cvt<<<dim3(8, 32), 256, 0, stream>>>(Wv, WTall, 2048, 512, 4608);
  transpose_cvt<<<dim3(2, 32), 256, 0, stream>>>(Wr, WTall, 2048, 128, 5120);
  transpose_cvt<<<dim3(32, 32), 256, 0, stream>>>(Wo, WoT, 2048, 2048, 0);

  // fused projection: [4096, 2048] @ [2048, 5248] -> qkva
  gemm_bt<bf16><<<41 * 32, 256, 0, stream>>>(hb, WTall, qkva, 4096, NPROJ, 2048);

  mask_kernel<<<4096, 128, 0, stream>>>(qkva, rnn, lng, lnb, Wd, maskb);
  qgate_kernel<<<4096, 256, 0, stream>>>(qkva, maskb, qw, cosT, sinT, wqb, sgb);
  k_kernel<<<1024, 256, 0, stream>>>(qkva, maskb, kw, cosT, sinT, wkb);
  vt_kernel<<<512, 256, 0, stream>>>(qkva, wvtb);

  attn_kernel<<<512, 256, 0, stream>>>(wqb, wkb, wvtb, sgb, wab);

  gemm_bt<float><<<16 * 32, 256, 0, stream>>>(wab, WoT, out, 4096, 2048, 2048);
}